// Round 3
// baseline (353.725 us; speedup 1.0000x reference)
//
#include <hip/hip_runtime.h>

#define EPS 1e-10f
#define FAR_DELTA 1e10f

// One ray per 16-lane group (4 rays/wave). Lane j owns samples [j*8, j*8+8).
// Single memory epoch: den/z float4 loads issue first, then the wave's 4
// feature rows (6 KB contiguous) stream into LDS via global_load_lds(16B)
// with no VGPR round-trip; they arrive while the scan runs. Per-lane weight
// and depth partials are folded before the cross-lane scan so z/alpha/t regs
// die early -> VGPR <= 64 -> full-occupancy capable (LDS caps at 24 waves/CU).
__global__ __launch_bounds__(256, 8) void volrend_kernel(
    const float* __restrict__ density,   // [N,128]
    const float* __restrict__ feature,   // [N,128,3]
    const float* __restrict__ depth,     // [N,128]
    float* __restrict__ feat_out,        // [N,3]
    float* __restrict__ depth_out,       // [N]
    int N)
{
    __shared__ __align__(16) float featLDS[4 * 1536];   // 24 KB: 4 waves x 4 rays x 384

    const int tid  = threadIdx.x;
    const int lane = tid & 63;
    const int wv   = tid >> 6;        // wave in block
    const int j    = lane & 15;       // sublane in ray group
    const int sub  = lane >> 4;       // ray slot in wave
    const int r0   = blockIdx.x * 16 + wv * 4;   // first ray of this wave
    const int ray  = r0 + sub;
    if (ray >= N) return;

    // ---- Epoch: issue ALL global traffic up front ----
    const float4* d4 = (const float4*)(density + (size_t)ray * 128 + j * 8);
    const float4* z4 = (const float4*)(depth   + (size_t)ray * 128 + j * 8);
    float4 dA = d4[0], dB = d4[1];
    float4 zA = z4[0], zB = z4[1];

    // Stage 4 rays' feature rows (6144 B contiguous) into this wave's LDS slab.
    {
        const char* gb = (const char*)(feature + (size_t)r0 * 384) + lane * 16;
        char*       lb = (char*)&featLDS[wv * 1536];
        #pragma unroll
        for (int i = 0; i < 6; ++i) {
            __builtin_amdgcn_global_load_lds(
                (const __attribute__((address_space(1))) void*)(gb + i * 1024),
                (__attribute__((address_space(3))) void*)(lb + i * 1024),
                16, 0, 0);
        }
    }

    float z[8]  = {zA.x, zA.y, zA.z, zA.w, zB.x, zB.y, zB.z, zB.w};
    float dn[8] = {dA.x, dA.y, dA.z, dA.w, dB.x, dB.y, dB.z, dB.w};

    // Seam depth: next lane's first sample (lane-relative +1 within the wave).
    float znext = __shfl_down(z[0], 1, 64);

    // Local pass: w_local[k] = alpha_k * prod(t_0..t_{k-1}) (lane-local),
    // fold depth partial now so z/alpha/t die before the scan.
    float wl[8];
    float tl  = 1.0f;     // running local product of t
    float adP = 0.0f;     // partial sum w_local * z
    #pragma unroll
    for (int k = 0; k < 8; ++k) {
        float delta = (k < 7) ? (z[k + 1] - z[k])
                              : ((j == 15) ? FAR_DELTA : (znext - z[7]));
        float ex = __expf(-fmaxf(dn[k], 0.0f) * delta);   // 1 - alpha
        float tk = ex + EPS;
        wl[k] = (1.0f - ex) * tl;
        adP  += wl[k] * z[k];
        tl   *= tk;
    }

    // Width-16 inclusive product scan of lane totals -> exclusive prefix.
    float s = tl;
    #pragma unroll
    for (int off = 1; off < 16; off <<= 1) {
        float v = __shfl_up(s, off, 16);
        if (j >= off) s *= v;
    }
    float excl = __shfl_up(s, 1, 16);
    if (j == 0) excl = 1.0f;

    // Features are staged by now (issued ~the whole scan ago).
    __syncthreads();

    const float4* fl = (const float4*)&featLDS[wv * 1536 + sub * 384 + j * 24];
    float4 F0 = fl[0], F1 = fl[1], F2 = fl[2], F3 = fl[3], F4 = fl[4], F5 = fl[5];
    float f[24] = {F0.x, F0.y, F0.z, F0.w, F1.x, F1.y, F1.z, F1.w,
                   F2.x, F2.y, F2.z, F2.w, F3.x, F3.y, F3.z, F3.w,
                   F4.x, F4.y, F4.z, F4.w, F5.x, F5.y, F5.z, F5.w};

    float a0 = 0.0f, a1 = 0.0f, a2 = 0.0f;
    #pragma unroll
    for (int k = 0; k < 8; ++k) {
        a0 += wl[k] * f[3 * k + 0];
        a1 += wl[k] * f[3 * k + 1];
        a2 += wl[k] * f[3 * k + 2];
    }

    // Scale by the lane-exclusive transmittance, then reduce across 16 lanes.
    a0 *= excl; a1 *= excl; a2 *= excl;
    float ad = adP * excl;

    #pragma unroll
    for (int off = 8; off >= 1; off >>= 1) {
        a0 += __shfl_xor(a0, off, 16);
        a1 += __shfl_xor(a1, off, 16);
        a2 += __shfl_xor(a2, off, 16);
        ad += __shfl_xor(ad, off, 16);
    }

    if (j == 0) {
        feat_out[(size_t)ray * 3 + 0] = a0;
        feat_out[(size_t)ray * 3 + 1] = a1;
        feat_out[(size_t)ray * 3 + 2] = a2;
        depth_out[ray] = ad;
    }
}

extern "C" void kernel_launch(void* const* d_in, const int* in_sizes, int n_in,
                              void* d_out, int out_size, void* d_ws, size_t ws_size,
                              hipStream_t stream) {
    const float* density = (const float*)d_in[0];   // [N,128]
    const float* feature = (const float*)d_in[1];   // [N,128,3]
    const float* depth   = (const float*)d_in[2];   // [N,128]

    const int P = 128;
    const int N = in_sizes[0] / P;                  // 131072

    float* feat_out  = (float*)d_out;                 // [N,3]
    float* depth_out = (float*)d_out + (size_t)N * 3; // [N]

    // 16 rays per block (4 waves x 4 rays each).
    dim3 grid((N + 15) / 16);
    dim3 block(256);
    volrend_kernel<<<grid, block, 0, stream>>>(density, feature, depth,
                                               feat_out, depth_out, N);
}